// Round 20
// baseline (134.116 us; speedup 1.0000x reference)
//
#include <hip/hip_runtime.h>

// RecallK via bf16 hi/lo split on matrix cores — R20: SYMMETRY HALVING.
// dot(x_i,x_j) ~= (hi_i+lo_i).hi_j  (R19's 2-term form, absmax 1.22e-4 verified).
// d(i,j)=d(j,i): upper-triangular 256x256 block grid (P<=Q over 64 panels), each
// pair computed once; results scattered to BOTH rows via packed u64 atomicMin:
//   key = ((u64)bits(d) << 14) | index   (d > 0 via sq+256 bias, R15-verified)
// atomicMin is commutative+idempotent -> deterministic, duplicate-safe (P==Q blocks
// run the full square row-side only), and d-ties resolve to smaller index = exact
// numpy first-min. Work: MFMA floor 66->34us, LDS reads 41->21us, staging halved.
// Block structure = R19 verbatim (4 tiles of 64 cols, 1-syncthreads-per-tile, P16
// layout, hi-bank-only B staging). Col-side epilogue (P<Q only): candidates
// sq_x - 2*acc per lane row, in-lane lex-min over 8 ascending rows, cross-lq
// shfl_xor(16,32), lq==0 lanes atomicMin into the column's key.
// Diag: only P==Q tiles t==w>>1 (wave-uniform) run the guarded path.
// P16 layout: chunk(g16,ks,l) = (g16*4+ks)*64+l holds X[g16*16+(l&15)][ks*32+(l>>4)*8..+8]

typedef __bf16 bf16x8 __attribute__((ext_vector_type(8)));
typedef float f32x4 __attribute__((ext_vector_type(4)));

#define NN 16384
#define MFMA16(A, B, C) __builtin_amdgcn_mfma_f32_16x16x32_bf16(A, B, C, 0, 0, 0)
#define GLDS(gsrc, ldst)                                                              \
  __builtin_amdgcn_global_load_lds((const __attribute__((address_space(1))) void*)(gsrc), \
                                   (__attribute__((address_space(3))) void*)(ldst), 16, 0, 0)

// --- per-row squared norms + 256 bias (keys must be positive for uint ordering) ---
__global__ __launch_bounds__(256) void sq_kernel(const float* __restrict__ feat,
                                                 float* __restrict__ sq) {
  int gid = blockIdx.x * 256 + threadIdx.x;
  int row = gid >> 6;
  int lane = threadIdx.x & 63;
  float2 v = reinterpret_cast<const float2*>(feat + (size_t)row * 128)[lane];
  float s = v.x * v.x + v.y * v.y;
#pragma unroll
  for (int off = 32; off > 0; off >>= 1) s += __shfl_xor(s, off, 64);
  if (lane == 0) sq[row] = s + 256.0f;  // d = sq_j+256-2dot in [~150,~620] > 0
}

// --- fp32 -> (hi,lo) bf16 banks in 16-row-group MFMA-chunk order ---
__global__ __launch_bounds__(256) void convert_kernel(const float* __restrict__ feat,
                                                      bf16x8* __restrict__ Ph,
                                                      bf16x8* __restrict__ Pl) {
  int chunk = blockIdx.x * 256 + threadIdx.x;  // 262144 chunks
  int l = chunk & 63;
  int ks = (chunk >> 6) & 3;
  int g = chunk >> 8;                          // 0..1023 (16-row groups)
  int row = g * 16 + (l & 15);
  int k0 = ks * 32 + (l >> 4) * 8;
  const float4* s = reinterpret_cast<const float4*>(feat + (size_t)row * 128 + k0);
  float4 v0 = s[0], v1 = s[1];
  float xs[8] = {v0.x, v0.y, v0.z, v0.w, v1.x, v1.y, v1.z, v1.w};
  bf16x8 hv, lv;
#pragma unroll
  for (int e = 0; e < 8; ++e) {
    float x = xs[e];
    __bf16 h = (__bf16)x;
    hv[e] = h;
    lv[e] = (__bf16)(x - (float)h);
  }
  Ph[chunk] = hv;
  Pl[chunk] = lv;
}

// --- main: 2080 blocks = upper-tri pairs of 64 panels; 8 waves x 32 rows ---
__global__ __launch_bounds__(512, 4) void nn_tri(const bf16x8* __restrict__ Ph,
                                                 const bf16x8* __restrict__ Pl,
                                                 const float* __restrict__ sq,
                                                 unsigned long long* __restrict__ rowKey) {
  __shared__ bf16x8 BhL[2][1024];  // [buf][cg*256 + ks*64 + lane]  2 x 16 KB = 32 KB
  // decode upper-triangle (P,Q)
  int b = blockIdx.x, P = 0;
  while (b >= 64 - P) { b -= 64 - P; ++P; }
  const int Q = P + b;
  const int tid = threadIdx.x;
  const int w = tid >> 6;          // wave 0..7; rows P*256 + w*32 .. +32
  const int lane = tid & 63;
  const int lq = lane >> 4;        // row-quad selector in C layout
  const int lc = lane & 15;        // col-in-group

  // A: two 16-row groups (32 rows x K=128, hi+lo): 16 frags = 64 VGPR
  bf16x8 Ah0[4], Al0[4], Ah1[4], Al1[4];
  {
    int gA = P * 16 + w * 2;
#pragma unroll
    for (int ks = 0; ks < 4; ++ks) {
      Ah0[ks] = Ph[(gA * 4 + ks) * 64 + lane];
      Al0[ks] = Pl[(gA * 4 + ks) * 64 + lane];
      Ah1[ks] = Ph[((gA + 1) * 4 + ks) * 64 + lane];
      Al1[ks] = Pl[((gA + 1) * 4 + ks) * 64 + lane];
    }
  }

  const int ig0 = P * 256 + w * 32 + lq * 4;  // + r = rowgroup0 rows; +16 = rowgroup1
  // biased sq of this lane's 8 A-rows (for col-side candidates)
  float sqA0[4], sqA1[4];
#pragma unroll
  for (int r = 0; r < 4; ++r) {
    sqA0[r] = sq[ig0 + r];
    sqA1[r] = sq[ig0 + 16 + r];
  }

  // stage one 64-col B tile (hi bank only) from Q-panel: 16 GLDS, 2 per wave.
  auto stage = [&](int nbuf, int tt) {
    const int cgi = w >> 1;
    const int gcol = Q * 16 + tt * 4 + cgi;
    const int ks0 = (w & 1) * 2;
    bf16x8* dst = &BhL[nbuf][cgi * 256];
#pragma unroll
    for (int ks = ks0; ks < ks0 + 2; ++ks) {
      size_t srcoff = ((size_t)((gcol * 4 + ks) * 64 + lane)) * 16;
      GLDS((const char*)Ph + srcoff, dst + ks * 64);
    }
  };

  float best0[4], best1[4];
  int bidx0[4], bidx1[4];
#pragma unroll
  for (int r = 0; r < 4; ++r) {
    best0[r] = 3.4e38f; best1[r] = 3.4e38f;
    bidx0[r] = 0; bidx1[r] = 0;
  }

  stage(0, 0);
  __syncthreads();  // full fence: stage complete + all waves synced

  int buf = 0;
  const int diagT = (P == Q) ? (w >> 1) : -1;  // the only tile that can contain self

  for (int t = 0; t < 4; ++t) {
    const int jb = Q * 256 + t * 64;
    float sqc[4];
#pragma unroll
    for (int cg = 0; cg < 4; ++cg) sqc[cg] = sq[jb + cg * 16 + lc];  // before stage
    if (t < 3) stage(buf ^ 1, t + 1);                                // counted vmcnt wait

#pragma unroll
    for (int cg = 0; cg < 4; ++cg) {
      f32x4 a0 = {}, a1 = {};
#pragma unroll
      for (int ks = 0; ks < 4; ++ks) {
        bf16x8 bh = BhL[buf][cg * 256 + ks * 64 + lane];
        a0 = MFMA16(Ah0[ks], bh, a0);
        a1 = MFMA16(Ah1[ks], bh, a1);
        a0 = MFMA16(Al0[ks], bh, a0);
        a1 = MFMA16(Al1[ks], bh, a1);
      }
      const int j = jb + cg * 16 + lc;
      // row-side: rows in P get candidate j (ascending cg,t + strict < = first-min)
      if (t != diagT) {
#pragma unroll
        for (int r = 0; r < 4; ++r) {
          float d0 = fmaf(-2.0f, a0[r], sqc[cg]);
          if (d0 < best0[r]) { best0[r] = d0; bidx0[r] = j; }
          float d1 = fmaf(-2.0f, a1[r], sqc[cg]);
          if (d1 < best1[r]) { best1[r] = d1; bidx1[r] = j; }
        }
      } else {  // wave-uniform diag tile: guard self column
#pragma unroll
        for (int r = 0; r < 4; ++r) {
          float d0 = fmaf(-2.0f, a0[r], sqc[cg]);
          if (j != ig0 + r && d0 < best0[r]) { best0[r] = d0; bidx0[r] = j; }
          float d1 = fmaf(-2.0f, a1[r], sqc[cg]);
          if (j != ig0 + 16 + r && d1 < best1[r]) { best1[r] = d1; bidx1[r] = j; }
        }
      }
      // col-side (P<Q only): column j gets candidates from this wave's 32 rows
      if (P != Q) {
        float m = fmaf(-2.0f, a0[0], sqA0[0]);
        int mi = ig0;
#pragma unroll
        for (int r = 1; r < 4; ++r) {  // in-lane rows ascending: strict < = first-min
          float d = fmaf(-2.0f, a0[r], sqA0[r]);
          if (d < m) { m = d; mi = ig0 + r; }
        }
#pragma unroll
        for (int r = 0; r < 4; ++r) {
          float d = fmaf(-2.0f, a1[r], sqA1[r]);
          if (d < m) { m = d; mi = ig0 + 16 + r; }
        }
        // cross-lq (lanes sharing col j): lex (d, row)
#pragma unroll
        for (int off = 16; off <= 32; off <<= 1) {
          float od = __shfl_xor(m, off);
          int oi = __shfl_xor(mi, off);
          if (od < m || (od == m && oi < mi)) { m = od; mi = oi; }
        }
        if (lq == 0) {
          unsigned long long key =
              ((unsigned long long)__builtin_bit_cast(unsigned int, m) << 14) |
              (unsigned long long)mi;
          atomicMin(&rowKey[j], key);
        }
      }
    }

    __syncthreads();  // drains my stage (vmcnt 0) + all waves done reading buf
    buf ^= 1;
  }

  // row-side finish: butterfly over 16 col-lanes, then atomicMin per row
#pragma unroll
  for (int r = 0; r < 4; ++r) {
    float d0 = best0[r], d1 = best1[r];
    int i0 = bidx0[r], i1 = bidx1[r];
#pragma unroll
    for (int off = 1; off < 16; off <<= 1) {
      float od = __shfl_xor(d0, off); int oi = __shfl_xor(i0, off);
      if (od < d0 || (od == d0 && oi < i0)) { d0 = od; i0 = oi; }
      od = __shfl_xor(d1, off); oi = __shfl_xor(i1, off);
      if (od < d1 || (od == d1 && oi < i1)) { d1 = od; i1 = oi; }
    }
    if (lc == 0) {
      unsigned long long k0 =
          ((unsigned long long)__builtin_bit_cast(unsigned int, d0) << 14) |
          (unsigned long long)i0;
      atomicMin(&rowKey[ig0 + r], k0);
      unsigned long long k1 =
          ((unsigned long long)__builtin_bit_cast(unsigned int, d1) << 14) |
          (unsigned long long)i1;
      atomicMin(&rowKey[ig0 + 16 + r], k1);
    }
  }
}

// --- count label matches from the packed keys ---
__global__ __launch_bounds__(256) void combine_kernel(const unsigned long long* __restrict__ rowKey,
                                                      const int* __restrict__ labels,
                                                      int* __restrict__ count) {
  int r = blockIdx.x * 256 + threadIdx.x;
  int i = (int)(rowKey[r] & 0x3FFFull);
  bool match = (labels[i] == labels[r]);
  unsigned long long mb = __ballot(match);
  if ((threadIdx.x & 63) == 0) atomicAdd(count, (int)__popcll(mb));
}

__global__ void finalize_kernel(const int* __restrict__ count, float* __restrict__ out) {
  out[0] = (float)(*count) * (1.0f / 16384.0f);
}

extern "C" void kernel_launch(void* const* d_in, const int* in_sizes, int n_in,
                              void* d_out, int out_size, void* d_ws, size_t ws_size,
                              hipStream_t stream) {
  const float* feat = (const float*)d_in[0];
  const int* labels = (const int*)d_in[1];
  float* out = (float*)d_out;
  char* ws = (char*)d_ws;

  int* count = (int*)ws;                                        // 4 B
  float* sq = (float*)(ws + 1024);                              // 64 KB
  unsigned long long* rowKey = (unsigned long long*)(ws + (1 << 19));  // 128 KB
  bf16x8* Ph = (bf16x8*)(ws + (2 << 20));                       // 4 MB
  bf16x8* Pl = (bf16x8*)(ws + (6 << 20));                       // 4 MB

  hipMemsetAsync(count, 0, sizeof(int), stream);
  hipMemsetAsync(rowKey, 0xFF, NN * sizeof(unsigned long long), stream);
  sq_kernel<<<NN / 4, 256, 0, stream>>>(feat, sq);
  convert_kernel<<<1024, 256, 0, stream>>>(feat, Ph, Pl);
  nn_tri<<<2080, 512, 0, stream>>>(Ph, Pl, sq, rowKey);
  combine_kernel<<<NN / 256, 256, 0, stream>>>(rowKey, labels, count);
  finalize_kernel<<<1, 1, 0, stream>>>(count, out);
}

// Round 21
// 131.759 us; speedup vs baseline: 1.0179x; 1.0179x over previous
//
#include <hip/hip_runtime.h>

// RecallK via bf16 hi/lo split on matrix cores — R21: symmetry + two-stage col scatter.
// dot(x_i,x_j) ~= (hi_i+lo_i).hi_j  (R19 2-term form). Upper-tri 256x256 block grid,
// each pair once; row-side keeps R19's register argmin; col-side scatters via packed
// u64 key = ((u64)bits(d)<<14)|index (d>0 by sq+256 bias; min = nearest, ties->smaller
// index = numpy first-min).
// R21 change vs R20: col-side atomics go to an LDS table colK[256] (ds_min_u64,
// few-cycle) and are flushed ONCE per column per block at the end -> global atomics
// 4.3M -> 533K (8x), WRITE_SIZE 61MB -> ~5MB. R20's counters showed the symmetry
// MFMA savings (MfmaUtil 23%) eaten by global-atomic churn (WRITE 61MB, hbm 907GB/s).
// All compute/layout/tie-break = R20 verbatim (absmax 6.1e-5 verified).
// P16 layout: chunk(g16,ks,l) = (g16*4+ks)*64+l holds X[g16*16+(l&15)][ks*32+(l>>4)*8..+8]

typedef __bf16 bf16x8 __attribute__((ext_vector_type(8)));
typedef float f32x4 __attribute__((ext_vector_type(4)));

#define NN 16384
#define MFMA16(A, B, C) __builtin_amdgcn_mfma_f32_16x16x32_bf16(A, B, C, 0, 0, 0)
#define GLDS(gsrc, ldst)                                                              \
  __builtin_amdgcn_global_load_lds((const __attribute__((address_space(1))) void*)(gsrc), \
                                   (__attribute__((address_space(3))) void*)(ldst), 16, 0, 0)

// --- per-row squared norms + 256 bias (keys must be positive for uint ordering) ---
__global__ __launch_bounds__(256) void sq_kernel(const float* __restrict__ feat,
                                                 float* __restrict__ sq) {
  int gid = blockIdx.x * 256 + threadIdx.x;
  int row = gid >> 6;
  int lane = threadIdx.x & 63;
  float2 v = reinterpret_cast<const float2*>(feat + (size_t)row * 128)[lane];
  float s = v.x * v.x + v.y * v.y;
#pragma unroll
  for (int off = 32; off > 0; off >>= 1) s += __shfl_xor(s, off, 64);
  if (lane == 0) sq[row] = s + 256.0f;  // d = sq_j+256-2dot in [~150,~620] > 0
}

// --- fp32 -> (hi,lo) bf16 banks in 16-row-group MFMA-chunk order ---
__global__ __launch_bounds__(256) void convert_kernel(const float* __restrict__ feat,
                                                      bf16x8* __restrict__ Ph,
                                                      bf16x8* __restrict__ Pl) {
  int chunk = blockIdx.x * 256 + threadIdx.x;  // 262144 chunks
  int l = chunk & 63;
  int ks = (chunk >> 6) & 3;
  int g = chunk >> 8;                          // 0..1023 (16-row groups)
  int row = g * 16 + (l & 15);
  int k0 = ks * 32 + (l >> 4) * 8;
  const float4* s = reinterpret_cast<const float4*>(feat + (size_t)row * 128 + k0);
  float4 v0 = s[0], v1 = s[1];
  float xs[8] = {v0.x, v0.y, v0.z, v0.w, v1.x, v1.y, v1.z, v1.w};
  bf16x8 hv, lv;
#pragma unroll
  for (int e = 0; e < 8; ++e) {
    float x = xs[e];
    __bf16 h = (__bf16)x;
    hv[e] = h;
    lv[e] = (__bf16)(x - (float)h);
  }
  Ph[chunk] = hv;
  Pl[chunk] = lv;
}

// --- main: 2080 blocks = upper-tri pairs of 64 panels; 8 waves x 32 rows ---
__global__ __launch_bounds__(512, 4) void nn_tri(const bf16x8* __restrict__ Ph,
                                                 const bf16x8* __restrict__ Pl,
                                                 const float* __restrict__ sq,
                                                 unsigned long long* __restrict__ rowKey) {
  __shared__ bf16x8 BhL[2][1024];          // 32 KB B staging
  __shared__ unsigned long long colK[256]; // 2 KB per-block column keys
  // decode upper-triangle (P,Q)
  int b = blockIdx.x, P = 0;
  while (b >= 64 - P) { b -= 64 - P; ++P; }
  const int Q = P + b;
  const int tid = threadIdx.x;
  const int w = tid >> 6;          // wave 0..7; rows P*256 + w*32 .. +32
  const int lane = tid & 63;
  const int lq = lane >> 4;        // row-quad selector in C layout
  const int lc = lane & 15;        // col-in-group

  // A: two 16-row groups (32 rows x K=128, hi+lo): 16 frags = 64 VGPR
  bf16x8 Ah0[4], Al0[4], Ah1[4], Al1[4];
  {
    int gA = P * 16 + w * 2;
#pragma unroll
    for (int ks = 0; ks < 4; ++ks) {
      Ah0[ks] = Ph[(gA * 4 + ks) * 64 + lane];
      Al0[ks] = Pl[(gA * 4 + ks) * 64 + lane];
      Ah1[ks] = Ph[((gA + 1) * 4 + ks) * 64 + lane];
      Al1[ks] = Pl[((gA + 1) * 4 + ks) * 64 + lane];
    }
  }

  const int ig0 = P * 256 + w * 32 + lq * 4;  // + r = rowgroup0 rows; +16 = rowgroup1
  // biased sq of this lane's 8 A-rows (for col-side candidates)
  float sqA0[4], sqA1[4];
#pragma unroll
  for (int r = 0; r < 4; ++r) {
    sqA0[r] = sq[ig0 + r];
    sqA1[r] = sq[ig0 + 16 + r];
  }

  // stage one 64-col B tile (hi bank only) from Q-panel: 16 GLDS, 2 per wave.
  auto stage = [&](int nbuf, int tt) {
    const int cgi = w >> 1;
    const int gcol = Q * 16 + tt * 4 + cgi;
    const int ks0 = (w & 1) * 2;
    bf16x8* dst = &BhL[nbuf][cgi * 256];
#pragma unroll
    for (int ks = ks0; ks < ks0 + 2; ++ks) {
      size_t srcoff = ((size_t)((gcol * 4 + ks) * 64 + lane)) * 16;
      GLDS((const char*)Ph + srcoff, dst + ks * 64);
    }
  };

  float best0[4], best1[4];
  int bidx0[4], bidx1[4];
#pragma unroll
  for (int r = 0; r < 4; ++r) {
    best0[r] = 3.4e38f; best1[r] = 3.4e38f;
    bidx0[r] = 0; bidx1[r] = 0;
  }

  if (tid < 256) colK[tid] = ~0ULL;  // init column table
  stage(0, 0);
  __syncthreads();  // full fence: stage + colK init complete, all waves synced

  int buf = 0;
  const int diagT = (P == Q) ? (w >> 1) : -1;  // the only tile that can contain self

  for (int t = 0; t < 4; ++t) {
    const int jb = Q * 256 + t * 64;
    float sqc[4];
#pragma unroll
    for (int cg = 0; cg < 4; ++cg) sqc[cg] = sq[jb + cg * 16 + lc];  // before stage
    if (t < 3) stage(buf ^ 1, t + 1);                                // counted vmcnt wait

#pragma unroll
    for (int cg = 0; cg < 4; ++cg) {
      f32x4 a0 = {}, a1 = {};
#pragma unroll
      for (int ks = 0; ks < 4; ++ks) {
        bf16x8 bh = BhL[buf][cg * 256 + ks * 64 + lane];
        a0 = MFMA16(Ah0[ks], bh, a0);
        a1 = MFMA16(Ah1[ks], bh, a1);
        a0 = MFMA16(Al0[ks], bh, a0);
        a1 = MFMA16(Al1[ks], bh, a1);
      }
      const int j = jb + cg * 16 + lc;
      // row-side: rows in P get candidate j (ascending cg,t + strict < = first-min)
      if (t != diagT) {
#pragma unroll
        for (int r = 0; r < 4; ++r) {
          float d0 = fmaf(-2.0f, a0[r], sqc[cg]);
          if (d0 < best0[r]) { best0[r] = d0; bidx0[r] = j; }
          float d1 = fmaf(-2.0f, a1[r], sqc[cg]);
          if (d1 < best1[r]) { best1[r] = d1; bidx1[r] = j; }
        }
      } else {  // wave-uniform diag tile: guard self column
#pragma unroll
        for (int r = 0; r < 4; ++r) {
          float d0 = fmaf(-2.0f, a0[r], sqc[cg]);
          if (j != ig0 + r && d0 < best0[r]) { best0[r] = d0; bidx0[r] = j; }
          float d1 = fmaf(-2.0f, a1[r], sqc[cg]);
          if (j != ig0 + 16 + r && d1 < best1[r]) { best1[r] = d1; bidx1[r] = j; }
        }
      }
      // col-side (P<Q only): column j gets candidates from this wave's 32 rows;
      // per-wave min -> LDS atomicMin (flushed to global once per column at end)
      if (P != Q) {
        float m = fmaf(-2.0f, a0[0], sqA0[0]);
        int mi = ig0;
#pragma unroll
        for (int r = 1; r < 4; ++r) {  // in-lane rows ascending: strict < = first-min
          float d = fmaf(-2.0f, a0[r], sqA0[r]);
          if (d < m) { m = d; mi = ig0 + r; }
        }
#pragma unroll
        for (int r = 0; r < 4; ++r) {
          float d = fmaf(-2.0f, a1[r], sqA1[r]);
          if (d < m) { m = d; mi = ig0 + 16 + r; }
        }
        // cross-lq (lanes sharing col j): lex (d, row)
#pragma unroll
        for (int off = 16; off <= 32; off <<= 1) {
          float od = __shfl_xor(m, off);
          int oi = __shfl_xor(mi, off);
          if (od < m || (od == m && oi < mi)) { m = od; mi = oi; }
        }
        if (lq == 0) {
          unsigned long long key =
              ((unsigned long long)__builtin_bit_cast(unsigned int, m) << 14) |
              (unsigned long long)mi;
          atomicMin(&colK[t * 64 + cg * 16 + lc], key);
        }
      }
    }

    __syncthreads();  // drains my stage (vmcnt 0) + all waves done reading buf
    buf ^= 1;
  }

  // col-side flush: one global atomic per column per block (loop ended at a barrier)
  if (P != Q && tid < 256) {
    atomicMin(&rowKey[Q * 256 + tid], colK[tid]);
  }

  // row-side finish: butterfly over 16 col-lanes, then atomicMin per row
#pragma unroll
  for (int r = 0; r < 4; ++r) {
    float d0 = best0[r], d1 = best1[r];
    int i0 = bidx0[r], i1 = bidx1[r];
#pragma unroll
    for (int off = 1; off < 16; off <<= 1) {
      float od = __shfl_xor(d0, off); int oi = __shfl_xor(i0, off);
      if (od < d0 || (od == d0 && oi < i0)) { d0 = od; i0 = oi; }
      od = __shfl_xor(d1, off); oi = __shfl_xor(i1, off);
      if (od < d1 || (od == d1 && oi < i1)) { d1 = od; i1 = oi; }
    }
    if (lc == 0) {
      unsigned long long k0 =
          ((unsigned long long)__builtin_bit_cast(unsigned int, d0) << 14) |
          (unsigned long long)i0;
      atomicMin(&rowKey[ig0 + r], k0);
      unsigned long long k1 =
          ((unsigned long long)__builtin_bit_cast(unsigned int, d1) << 14) |
          (unsigned long long)i1;
      atomicMin(&rowKey[ig0 + 16 + r], k1);
    }
  }
}

// --- count label matches from the packed keys ---
__global__ __launch_bounds__(256) void combine_kernel(const unsigned long long* __restrict__ rowKey,
                                                      const int* __restrict__ labels,
                                                      int* __restrict__ count) {
  int r = blockIdx.x * 256 + threadIdx.x;
  int i = (int)(rowKey[r] & 0x3FFFull);
  bool match = (labels[i] == labels[r]);
  unsigned long long mb = __ballot(match);
  if ((threadIdx.x & 63) == 0) atomicAdd(count, (int)__popcll(mb));
}

__global__ void finalize_kernel(const int* __restrict__ count, float* __restrict__ out) {
  out[0] = (float)(*count) * (1.0f / 16384.0f);
}

extern "C" void kernel_launch(void* const* d_in, const int* in_sizes, int n_in,
                              void* d_out, int out_size, void* d_ws, size_t ws_size,
                              hipStream_t stream) {
  const float* feat = (const float*)d_in[0];
  const int* labels = (const int*)d_in[1];
  float* out = (float*)d_out;
  char* ws = (char*)d_ws;

  int* count = (int*)ws;                                        // 4 B
  float* sq = (float*)(ws + 1024);                              // 64 KB
  unsigned long long* rowKey = (unsigned long long*)(ws + (1 << 19));  // 128 KB
  bf16x8* Ph = (bf16x8*)(ws + (2 << 20));                       // 4 MB
  bf16x8* Pl = (bf16x8*)(ws + (6 << 20));                       // 4 MB

  hipMemsetAsync(count, 0, sizeof(int), stream);
  hipMemsetAsync(rowKey, 0xFF, NN * sizeof(unsigned long long), stream);
  sq_kernel<<<NN / 4, 256, 0, stream>>>(feat, sq);
  convert_kernel<<<1024, 256, 0, stream>>>(feat, Ph, Pl);
  nn_tri<<<2080, 512, 0, stream>>>(Ph, Pl, sq, rowKey);
  combine_kernel<<<NN / 256, 256, 0, stream>>>(rowKey, labels, count);
  finalize_kernel<<<1, 1, 0, stream>>>(count, out);
}

// Round 22
// 128.867 us; speedup vs baseline: 1.0407x; 1.0224x over previous
//
#include <hip/hip_runtime.h>

// RecallK via bf16 hi/lo split on matrix cores — R22: consolidation.
// nn_tri = R21 verbatim (best: 123us nn / 131.8 total, absmax 6.1e-5).
// Change: sq_kernel fused into convert_kernel (each convert block owns exactly one
// 16-row group; deterministic LDS tree reduction -> sq[g*16+r] = sum(x^2)+256).
// Saves one launch + one full 8MB feat read (~4us of the 8.4us non-nn overhead).
// Session plateau note: nn residual (123us vs 34us MFMA floor) is VALU/overhead-
// bound per (unreliable) derived counters; 8 structural levers exhausted — the
// wins were the 2-term dot (R18/R19) and symmetry halving (R20/R21, net ~1%).
// dot(x_i,x_j) ~= (hi_i+lo_i).hi_j ; d = sq_j+256-2dot > 0; packed u64 key
// ((u64)bits(d)<<14)|index, atomicMin = deterministic first-min (numpy semantics).
// P16 layout: chunk(g16,ks,l) = (g16*4+ks)*64+l holds X[g16*16+(l&15)][ks*32+(l>>4)*8..+8]

typedef __bf16 bf16x8 __attribute__((ext_vector_type(8)));
typedef float f32x4 __attribute__((ext_vector_type(4)));

#define NN 16384
#define MFMA16(A, B, C) __builtin_amdgcn_mfma_f32_16x16x32_bf16(A, B, C, 0, 0, 0)
#define GLDS(gsrc, ldst)                                                              \
  __builtin_amdgcn_global_load_lds((const __attribute__((address_space(1))) void*)(gsrc), \
                                   (__attribute__((address_space(3))) void*)(ldst), 16, 0, 0)

// --- fp32 -> (hi,lo) bf16 banks in 16-row-group MFMA-chunk order + fused sq ---
// block bid owns chunks [bid*256, bid*256+256) == 16-row group g = bid exactly;
// row r is read by 16 threads (4 ks x 4 l-hi) -> deterministic per-row reduction.
__global__ __launch_bounds__(256) void convert_kernel(const float* __restrict__ feat,
                                                      bf16x8* __restrict__ Ph,
                                                      bf16x8* __restrict__ Pl,
                                                      float* __restrict__ sq) {
  __shared__ float red[16][16];
  int tid = threadIdx.x;
  int chunk = blockIdx.x * 256 + tid;
  int l = chunk & 63;
  int ks = (chunk >> 6) & 3;
  int g = blockIdx.x;                          // == chunk >> 8 for tid < 256
  int row = g * 16 + (l & 15);
  int k0 = ks * 32 + (l >> 4) * 8;
  const float4* s = reinterpret_cast<const float4*>(feat + (size_t)row * 128 + k0);
  float4 v0 = s[0], v1 = s[1];
  float xs[8] = {v0.x, v0.y, v0.z, v0.w, v1.x, v1.y, v1.z, v1.w};
  bf16x8 hv, lv;
  float ss = 0.f;
#pragma unroll
  for (int e = 0; e < 8; ++e) {
    float x = xs[e];
    __bf16 h = (__bf16)x;
    hv[e] = h;
    lv[e] = (__bf16)(x - (float)h);
    ss = fmaf(x, x, ss);
  }
  Ph[chunk] = hv;
  Pl[chunk] = lv;
  red[l & 15][ks * 4 + (l >> 4)] = ss;  // bijective slot per row
  __syncthreads();
  if (tid < 16) {
    float acc = 0.f;
#pragma unroll
    for (int q = 0; q < 16; ++q) acc += red[tid][q];  // fixed order: deterministic
    sq[g * 16 + tid] = acc + 256.0f;  // bias: d = sq_j+256-2dot in [~150,~620] > 0
  }
}

// --- main: 2080 blocks = upper-tri pairs of 64 panels; 8 waves x 32 rows ---
__global__ __launch_bounds__(512, 4) void nn_tri(const bf16x8* __restrict__ Ph,
                                                 const bf16x8* __restrict__ Pl,
                                                 const float* __restrict__ sq,
                                                 unsigned long long* __restrict__ rowKey) {
  __shared__ bf16x8 BhL[2][1024];          // 32 KB B staging
  __shared__ unsigned long long colK[256]; // 2 KB per-block column keys
  // decode upper-triangle (P,Q)
  int b = blockIdx.x, P = 0;
  while (b >= 64 - P) { b -= 64 - P; ++P; }
  const int Q = P + b;
  const int tid = threadIdx.x;
  const int w = tid >> 6;          // wave 0..7; rows P*256 + w*32 .. +32
  const int lane = tid & 63;
  const int lq = lane >> 4;        // row-quad selector in C layout
  const int lc = lane & 15;        // col-in-group

  // A: two 16-row groups (32 rows x K=128, hi+lo): 16 frags = 64 VGPR
  bf16x8 Ah0[4], Al0[4], Ah1[4], Al1[4];
  {
    int gA = P * 16 + w * 2;
#pragma unroll
    for (int ks = 0; ks < 4; ++ks) {
      Ah0[ks] = Ph[(gA * 4 + ks) * 64 + lane];
      Al0[ks] = Pl[(gA * 4 + ks) * 64 + lane];
      Ah1[ks] = Ph[((gA + 1) * 4 + ks) * 64 + lane];
      Al1[ks] = Pl[((gA + 1) * 4 + ks) * 64 + lane];
    }
  }

  const int ig0 = P * 256 + w * 32 + lq * 4;  // + r = rowgroup0 rows; +16 = rowgroup1
  // biased sq of this lane's 8 A-rows (for col-side candidates)
  float sqA0[4], sqA1[4];
#pragma unroll
  for (int r = 0; r < 4; ++r) {
    sqA0[r] = sq[ig0 + r];
    sqA1[r] = sq[ig0 + 16 + r];
  }

  // stage one 64-col B tile (hi bank only) from Q-panel: 16 GLDS, 2 per wave.
  auto stage = [&](int nbuf, int tt) {
    const int cgi = w >> 1;
    const int gcol = Q * 16 + tt * 4 + cgi;
    const int ks0 = (w & 1) * 2;
    bf16x8* dst = &BhL[nbuf][cgi * 256];
#pragma unroll
    for (int ks = ks0; ks < ks0 + 2; ++ks) {
      size_t srcoff = ((size_t)((gcol * 4 + ks) * 64 + lane)) * 16;
      GLDS((const char*)Ph + srcoff, dst + ks * 64);
    }
  };

  float best0[4], best1[4];
  int bidx0[4], bidx1[4];
#pragma unroll
  for (int r = 0; r < 4; ++r) {
    best0[r] = 3.4e38f; best1[r] = 3.4e38f;
    bidx0[r] = 0; bidx1[r] = 0;
  }

  if (tid < 256) colK[tid] = ~0ULL;  // init column table
  stage(0, 0);
  __syncthreads();  // full fence: stage + colK init complete, all waves synced

  int buf = 0;
  const int diagT = (P == Q) ? (w >> 1) : -1;  // the only tile that can contain self

  for (int t = 0; t < 4; ++t) {
    const int jb = Q * 256 + t * 64;
    float sqc[4];
#pragma unroll
    for (int cg = 0; cg < 4; ++cg) sqc[cg] = sq[jb + cg * 16 + lc];  // before stage
    if (t < 3) stage(buf ^ 1, t + 1);                                // counted vmcnt wait

#pragma unroll
    for (int cg = 0; cg < 4; ++cg) {
      f32x4 a0 = {}, a1 = {};
#pragma unroll
      for (int ks = 0; ks < 4; ++ks) {
        bf16x8 bh = BhL[buf][cg * 256 + ks * 64 + lane];
        a0 = MFMA16(Ah0[ks], bh, a0);
        a1 = MFMA16(Ah1[ks], bh, a1);
        a0 = MFMA16(Al0[ks], bh, a0);
        a1 = MFMA16(Al1[ks], bh, a1);
      }
      const int j = jb + cg * 16 + lc;
      // row-side: rows in P get candidate j (ascending cg,t + strict < = first-min)
      if (t != diagT) {
#pragma unroll
        for (int r = 0; r < 4; ++r) {
          float d0 = fmaf(-2.0f, a0[r], sqc[cg]);
          if (d0 < best0[r]) { best0[r] = d0; bidx0[r] = j; }
          float d1 = fmaf(-2.0f, a1[r], sqc[cg]);
          if (d1 < best1[r]) { best1[r] = d1; bidx1[r] = j; }
        }
      } else {  // wave-uniform diag tile: guard self column
#pragma unroll
        for (int r = 0; r < 4; ++r) {
          float d0 = fmaf(-2.0f, a0[r], sqc[cg]);
          if (j != ig0 + r && d0 < best0[r]) { best0[r] = d0; bidx0[r] = j; }
          float d1 = fmaf(-2.0f, a1[r], sqc[cg]);
          if (j != ig0 + 16 + r && d1 < best1[r]) { best1[r] = d1; bidx1[r] = j; }
        }
      }
      // col-side (P<Q only): column j gets candidates from this wave's 32 rows;
      // per-wave min -> LDS atomicMin (flushed to global once per column at end)
      if (P != Q) {
        float m = fmaf(-2.0f, a0[0], sqA0[0]);
        int mi = ig0;
#pragma unroll
        for (int r = 1; r < 4; ++r) {  // in-lane rows ascending: strict < = first-min
          float d = fmaf(-2.0f, a0[r], sqA0[r]);
          if (d < m) { m = d; mi = ig0 + r; }
        }
#pragma unroll
        for (int r = 0; r < 4; ++r) {
          float d = fmaf(-2.0f, a1[r], sqA1[r]);
          if (d < m) { m = d; mi = ig0 + 16 + r; }
        }
        // cross-lq (lanes sharing col j): lex (d, row)
#pragma unroll
        for (int off = 16; off <= 32; off <<= 1) {
          float od = __shfl_xor(m, off);
          int oi = __shfl_xor(mi, off);
          if (od < m || (od == m && oi < mi)) { m = od; mi = oi; }
        }
        if (lq == 0) {
          unsigned long long key =
              ((unsigned long long)__builtin_bit_cast(unsigned int, m) << 14) |
              (unsigned long long)mi;
          atomicMin(&colK[t * 64 + cg * 16 + lc], key);
        }
      }
    }

    __syncthreads();  // drains my stage (vmcnt 0) + all waves done reading buf
    buf ^= 1;
  }

  // col-side flush: one global atomic per column per block (loop ended at a barrier)
  if (P != Q && tid < 256) {
    atomicMin(&rowKey[Q * 256 + tid], colK[tid]);
  }

  // row-side finish: butterfly over 16 col-lanes, then atomicMin per row
#pragma unroll
  for (int r = 0; r < 4; ++r) {
    float d0 = best0[r], d1 = best1[r];
    int i0 = bidx0[r], i1 = bidx1[r];
#pragma unroll
    for (int off = 1; off < 16; off <<= 1) {
      float od = __shfl_xor(d0, off); int oi = __shfl_xor(i0, off);
      if (od < d0 || (od == d0 && oi < i0)) { d0 = od; i0 = oi; }
      od = __shfl_xor(d1, off); oi = __shfl_xor(i1, off);
      if (od < d1 || (od == d1 && oi < i1)) { d1 = od; i1 = oi; }
    }
    if (lc == 0) {
      unsigned long long k0 =
          ((unsigned long long)__builtin_bit_cast(unsigned int, d0) << 14) |
          (unsigned long long)i0;
      atomicMin(&rowKey[ig0 + r], k0);
      unsigned long long k1 =
          ((unsigned long long)__builtin_bit_cast(unsigned int, d1) << 14) |
          (unsigned long long)i1;
      atomicMin(&rowKey[ig0 + 16 + r], k1);
    }
  }
}

// --- count label matches from the packed keys ---
__global__ __launch_bounds__(256) void combine_kernel(const unsigned long long* __restrict__ rowKey,
                                                      const int* __restrict__ labels,
                                                      int* __restrict__ count) {
  int r = blockIdx.x * 256 + threadIdx.x;
  int i = (int)(rowKey[r] & 0x3FFFull);
  bool match = (labels[i] == labels[r]);
  unsigned long long mb = __ballot(match);
  if ((threadIdx.x & 63) == 0) atomicAdd(count, (int)__popcll(mb));
}

__global__ void finalize_kernel(const int* __restrict__ count, float* __restrict__ out) {
  out[0] = (float)(*count) * (1.0f / 16384.0f);
}

extern "C" void kernel_launch(void* const* d_in, const int* in_sizes, int n_in,
                              void* d_out, int out_size, void* d_ws, size_t ws_size,
                              hipStream_t stream) {
  const float* feat = (const float*)d_in[0];
  const int* labels = (const int*)d_in[1];
  float* out = (float*)d_out;
  char* ws = (char*)d_ws;

  int* count = (int*)ws;                                        // 4 B
  float* sq = (float*)(ws + 1024);                              // 64 KB
  unsigned long long* rowKey = (unsigned long long*)(ws + (1 << 19));  // 128 KB
  bf16x8* Ph = (bf16x8*)(ws + (2 << 20));                       // 4 MB
  bf16x8* Pl = (bf16x8*)(ws + (6 << 20));                       // 4 MB

  hipMemsetAsync(count, 0, sizeof(int), stream);
  hipMemsetAsync(rowKey, 0xFF, NN * sizeof(unsigned long long), stream);
  convert_kernel<<<1024, 256, 0, stream>>>(feat, Ph, Pl, sq);
  nn_tri<<<2080, 512, 0, stream>>>(Ph, Pl, sq, rowKey);
  combine_kernel<<<NN / 256, 256, 0, stream>>>(rowKey, labels, count);
  finalize_kernel<<<1, 1, 0, stream>>>(count, out);
}

// Round 23
// 110.116 us; speedup vs baseline: 1.2180x; 1.1703x over previous
//
#include <hip/hip_runtime.h>

// RecallK via bf16 hi/lo split on matrix cores — R23: col-side shfl deletion.
// nn_tri = R22 except: the cross-lq butterfly before the colK atomicMin is removed;
// all 4 lq-lanes atomicMin their own packed key directly. Semantics identical:
// key = ((u64)bits(d)<<14)|rowIndex already orders (d, row) lexicographically, so
// min over 4 keys == shfl-reduce-then-min. Deletes ~10 VALU ops x 16 cg-visits/tile
// from the hot loop (VALU = largest consumer: ~58us of 123); LDS-atomic pipe (idle)
// absorbs 3 extra atomics/col/cg. Output must be bit-identical (absmax 6.103516e-5).
// dot(x_i,x_j) ~= (hi_i+lo_i).hi_j ; d = sq_j+256-2dot > 0; atomicMin = deterministic
// first-min (numpy semantics). Convert+sq fused (R22).
// P16 layout: chunk(g16,ks,l) = (g16*4+ks)*64+l holds X[g16*16+(l&15)][ks*32+(l>>4)*8..+8]

typedef __bf16 bf16x8 __attribute__((ext_vector_type(8)));
typedef float f32x4 __attribute__((ext_vector_type(4)));

#define NN 16384
#define MFMA16(A, B, C) __builtin_amdgcn_mfma_f32_16x16x32_bf16(A, B, C, 0, 0, 0)
#define GLDS(gsrc, ldst)                                                              \
  __builtin_amdgcn_global_load_lds((const __attribute__((address_space(1))) void*)(gsrc), \
                                   (__attribute__((address_space(3))) void*)(ldst), 16, 0, 0)

// --- fp32 -> (hi,lo) bf16 banks in 16-row-group MFMA-chunk order + fused sq ---
__global__ __launch_bounds__(256) void convert_kernel(const float* __restrict__ feat,
                                                      bf16x8* __restrict__ Ph,
                                                      bf16x8* __restrict__ Pl,
                                                      float* __restrict__ sq) {
  __shared__ float red[16][16];
  int tid = threadIdx.x;
  int chunk = blockIdx.x * 256 + tid;
  int l = chunk & 63;
  int ks = (chunk >> 6) & 3;
  int g = blockIdx.x;
  int row = g * 16 + (l & 15);
  int k0 = ks * 32 + (l >> 4) * 8;
  const float4* s = reinterpret_cast<const float4*>(feat + (size_t)row * 128 + k0);
  float4 v0 = s[0], v1 = s[1];
  float xs[8] = {v0.x, v0.y, v0.z, v0.w, v1.x, v1.y, v1.z, v1.w};
  bf16x8 hv, lv;
  float ss = 0.f;
#pragma unroll
  for (int e = 0; e < 8; ++e) {
    float x = xs[e];
    __bf16 h = (__bf16)x;
    hv[e] = h;
    lv[e] = (__bf16)(x - (float)h);
    ss = fmaf(x, x, ss);
  }
  Ph[chunk] = hv;
  Pl[chunk] = lv;
  red[l & 15][ks * 4 + (l >> 4)] = ss;  // bijective slot per row
  __syncthreads();
  if (tid < 16) {
    float acc = 0.f;
#pragma unroll
    for (int q = 0; q < 16; ++q) acc += red[tid][q];  // fixed order: deterministic
    sq[g * 16 + tid] = acc + 256.0f;  // bias: d = sq_j+256-2dot in [~150,~620] > 0
  }
}

// --- main: 2080 blocks = upper-tri pairs of 64 panels; 8 waves x 32 rows ---
__global__ __launch_bounds__(512, 4) void nn_tri(const bf16x8* __restrict__ Ph,
                                                 const bf16x8* __restrict__ Pl,
                                                 const float* __restrict__ sq,
                                                 unsigned long long* __restrict__ rowKey) {
  __shared__ bf16x8 BhL[2][1024];          // 32 KB B staging
  __shared__ unsigned long long colK[256]; // 2 KB per-block column keys
  // decode upper-triangle (P,Q)
  int b = blockIdx.x, P = 0;
  while (b >= 64 - P) { b -= 64 - P; ++P; }
  const int Q = P + b;
  const int tid = threadIdx.x;
  const int w = tid >> 6;          // wave 0..7; rows P*256 + w*32 .. +32
  const int lane = tid & 63;
  const int lq = lane >> 4;        // row-quad selector in C layout
  const int lc = lane & 15;        // col-in-group

  // A: two 16-row groups (32 rows x K=128, hi+lo): 16 frags = 64 VGPR
  bf16x8 Ah0[4], Al0[4], Ah1[4], Al1[4];
  {
    int gA = P * 16 + w * 2;
#pragma unroll
    for (int ks = 0; ks < 4; ++ks) {
      Ah0[ks] = Ph[(gA * 4 + ks) * 64 + lane];
      Al0[ks] = Pl[(gA * 4 + ks) * 64 + lane];
      Ah1[ks] = Ph[((gA + 1) * 4 + ks) * 64 + lane];
      Al1[ks] = Pl[((gA + 1) * 4 + ks) * 64 + lane];
    }
  }

  const int ig0 = P * 256 + w * 32 + lq * 4;  // + r = rowgroup0 rows; +16 = rowgroup1
  // biased sq of this lane's 8 A-rows (for col-side candidates)
  float sqA0[4], sqA1[4];
#pragma unroll
  for (int r = 0; r < 4; ++r) {
    sqA0[r] = sq[ig0 + r];
    sqA1[r] = sq[ig0 + 16 + r];
  }

  // stage one 64-col B tile (hi bank only) from Q-panel: 16 GLDS, 2 per wave.
  auto stage = [&](int nbuf, int tt) {
    const int cgi = w >> 1;
    const int gcol = Q * 16 + tt * 4 + cgi;
    const int ks0 = (w & 1) * 2;
    bf16x8* dst = &BhL[nbuf][cgi * 256];
#pragma unroll
    for (int ks = ks0; ks < ks0 + 2; ++ks) {
      size_t srcoff = ((size_t)((gcol * 4 + ks) * 64 + lane)) * 16;
      GLDS((const char*)Ph + srcoff, dst + ks * 64);
    }
  };

  float best0[4], best1[4];
  int bidx0[4], bidx1[4];
#pragma unroll
  for (int r = 0; r < 4; ++r) {
    best0[r] = 3.4e38f; best1[r] = 3.4e38f;
    bidx0[r] = 0; bidx1[r] = 0;
  }

  if (tid < 256) colK[tid] = ~0ULL;  // init column table
  stage(0, 0);
  __syncthreads();  // full fence: stage + colK init complete, all waves synced

  int buf = 0;
  const int diagT = (P == Q) ? (w >> 1) : -1;  // the only tile that can contain self

  for (int t = 0; t < 4; ++t) {
    const int jb = Q * 256 + t * 64;
    float sqc[4];
#pragma unroll
    for (int cg = 0; cg < 4; ++cg) sqc[cg] = sq[jb + cg * 16 + lc];  // before stage
    if (t < 3) stage(buf ^ 1, t + 1);                                // counted vmcnt wait

#pragma unroll
    for (int cg = 0; cg < 4; ++cg) {
      f32x4 a0 = {}, a1 = {};
#pragma unroll
      for (int ks = 0; ks < 4; ++ks) {
        bf16x8 bh = BhL[buf][cg * 256 + ks * 64 + lane];
        a0 = MFMA16(Ah0[ks], bh, a0);
        a1 = MFMA16(Ah1[ks], bh, a1);
        a0 = MFMA16(Al0[ks], bh, a0);
        a1 = MFMA16(Al1[ks], bh, a1);
      }
      const int j = jb + cg * 16 + lc;
      // row-side: rows in P get candidate j (ascending cg,t + strict < = first-min)
      if (t != diagT) {
#pragma unroll
        for (int r = 0; r < 4; ++r) {
          float d0 = fmaf(-2.0f, a0[r], sqc[cg]);
          if (d0 < best0[r]) { best0[r] = d0; bidx0[r] = j; }
          float d1 = fmaf(-2.0f, a1[r], sqc[cg]);
          if (d1 < best1[r]) { best1[r] = d1; bidx1[r] = j; }
        }
      } else {  // wave-uniform diag tile: guard self column
#pragma unroll
        for (int r = 0; r < 4; ++r) {
          float d0 = fmaf(-2.0f, a0[r], sqc[cg]);
          if (j != ig0 + r && d0 < best0[r]) { best0[r] = d0; bidx0[r] = j; }
          float d1 = fmaf(-2.0f, a1[r], sqc[cg]);
          if (j != ig0 + 16 + r && d1 < best1[r]) { best1[r] = d1; bidx1[r] = j; }
        }
      }
      // col-side (P<Q only): per-lane min over its 8 rows, then DIRECT LDS atomicMin
      // from all 4 lq-lanes (key encodes (d,row) lex order -> identical result to the
      // former shfl-reduce, ~10 fewer VALU ops per cg)
      if (P != Q) {
        float m = fmaf(-2.0f, a0[0], sqA0[0]);
        int mi = ig0;
#pragma unroll
        for (int r = 1; r < 4; ++r) {  // in-lane rows ascending: strict < = first-min
          float d = fmaf(-2.0f, a0[r], sqA0[r]);
          if (d < m) { m = d; mi = ig0 + r; }
        }
#pragma unroll
        for (int r = 0; r < 4; ++r) {
          float d = fmaf(-2.0f, a1[r], sqA1[r]);
          if (d < m) { m = d; mi = ig0 + 16 + r; }
        }
        unsigned long long key =
            ((unsigned long long)__builtin_bit_cast(unsigned int, m) << 14) |
            (unsigned long long)mi;
        atomicMin(&colK[t * 64 + cg * 16 + lc], key);
      }
    }

    __syncthreads();  // drains my stage (vmcnt 0) + all waves done reading buf
    buf ^= 1;
  }

  // col-side flush: one global atomic per column per block (loop ended at a barrier)
  if (P != Q && tid < 256) {
    atomicMin(&rowKey[Q * 256 + tid], colK[tid]);
  }

  // row-side finish: butterfly over 16 col-lanes, then atomicMin per row
#pragma unroll
  for (int r = 0; r < 4; ++r) {
    float d0 = best0[r], d1 = best1[r];
    int i0 = bidx0[r], i1 = bidx1[r];
#pragma unroll
    for (int off = 1; off < 16; off <<= 1) {
      float od = __shfl_xor(d0, off); int oi = __shfl_xor(i0, off);
      if (od < d0 || (od == d0 && oi < i0)) { d0 = od; i0 = oi; }
      od = __shfl_xor(d1, off); oi = __shfl_xor(i1, off);
      if (od < d1 || (od == d1 && oi < i1)) { d1 = od; i1 = oi; }
    }
    if (lc == 0) {
      unsigned long long k0 =
          ((unsigned long long)__builtin_bit_cast(unsigned int, d0) << 14) |
          (unsigned long long)i0;
      atomicMin(&rowKey[ig0 + r], k0);
      unsigned long long k1 =
          ((unsigned long long)__builtin_bit_cast(unsigned int, d1) << 14) |
          (unsigned long long)i1;
      atomicMin(&rowKey[ig0 + 16 + r], k1);
    }
  }
}

// --- count label matches from the packed keys ---
__global__ __launch_bounds__(256) void combine_kernel(const unsigned long long* __restrict__ rowKey,
                                                      const int* __restrict__ labels,
                                                      int* __restrict__ count) {
  int r = blockIdx.x * 256 + threadIdx.x;
  int i = (int)(rowKey[r] & 0x3FFFull);
  bool match = (labels[i] == labels[r]);
  unsigned long long mb = __ballot(match);
  if ((threadIdx.x & 63) == 0) atomicAdd(count, (int)__popcll(mb));
}

__global__ void finalize_kernel(const int* __restrict__ count, float* __restrict__ out) {
  out[0] = (float)(*count) * (1.0f / 16384.0f);
}

extern "C" void kernel_launch(void* const* d_in, const int* in_sizes, int n_in,
                              void* d_out, int out_size, void* d_ws, size_t ws_size,
                              hipStream_t stream) {
  const float* feat = (const float*)d_in[0];
  const int* labels = (const int*)d_in[1];
  float* out = (float*)d_out;
  char* ws = (char*)d_ws;

  int* count = (int*)ws;                                        // 4 B
  float* sq = (float*)(ws + 1024);                              // 64 KB
  unsigned long long* rowKey = (unsigned long long*)(ws + (1 << 19));  // 128 KB
  bf16x8* Ph = (bf16x8*)(ws + (2 << 20));                       // 4 MB
  bf16x8* Pl = (bf16x8*)(ws + (6 << 20));                       // 4 MB

  hipMemsetAsync(count, 0, sizeof(int), stream);
  hipMemsetAsync(rowKey, 0xFF, NN * sizeof(unsigned long long), stream);
  convert_kernel<<<1024, 256, 0, stream>>>(feat, Ph, Pl, sq);
  nn_tri<<<2080, 512, 0, stream>>>(Ph, Pl, sq, rowKey);
  combine_kernel<<<NN / 256, 256, 0, stream>>>(rowKey, labels, count);
  finalize_kernel<<<1, 1, 0, stream>>>(count, out);
}